// Round 1
// baseline (1245.131 us; speedup 1.0000x reference)
//
#include <hip/hip_runtime.h>
#include <hip/hip_bf16.h>
#include <math.h>

// Problem constants
#define B 32
#define N 128
#define BT (B*N)          // 4096
#define WD 100
#define UD 25
#define D 125             // LSTM hidden per direction
#define G4 (4*D)          // 500 gates
#define H2 (2*D)          // 250
#define HID 100
#define L 50

// ---------------------------------------------------------------------------
// K1: embedding gather  words[bt][0:100]=wlookup[wid], [100:125]=tlookup[uid]
// ---------------------------------------------------------------------------
__global__ void embed_kernel(const int* __restrict__ wids, const int* __restrict__ uids,
                             const float* __restrict__ wl, const float* __restrict__ tl,
                             float* __restrict__ words) {
    int bt = blockIdx.x;
    int t = threadIdx.x;           // 128 threads
    int wid = wids[bt];
    int uid = uids[bt];
    if (t < WD)       words[bt*D + t] = wl[wid*WD + t];
    else if (t < D)   words[bt*D + t] = tl[uid*UD + (t - WD)];
}

// ---------------------------------------------------------------------------
// K2: projection GEMM  out[m][n] = sum_k x[row(m)][k]*W[n][k] + bias[n]
//     M=4096 rows, MT=16 rows per block, thread n computes one column.
//     gather_idx != null => row(m) = b*128 + (n_pos==0 ? 0 : gather_idx[m])
// ---------------------------------------------------------------------------
#define MT 16
__global__ void proj_kernel(const float* __restrict__ x, const float* __restrict__ W,
                            const float* __restrict__ bias, float* __restrict__ out,
                            int Ncols, int K, const int* __restrict__ gather_idx) {
    __shared__ __align__(16) float xs[MT * 250];   // layout xs[k*MT + r]
    int m0 = blockIdx.x * MT;
    // cooperative stage of MT input rows
    for (int e = threadIdx.x; e < MT * K; e += blockDim.x) {
        int k = e / MT;
        int r = e % MT;
        int m = m0 + r;
        int row = m;
        if (gather_idx) {
            int b = m >> 7, npos = m & 127;
            int tgt = (npos == 0) ? 0 : gather_idx[m];
            row = (b << 7) + tgt;
        }
        xs[k*MT + r] = x[row*K + k];
    }
    __syncthreads();
    int n = threadIdx.x;
    if (n < Ncols) {
        float acc[MT];
        #pragma unroll
        for (int r = 0; r < MT; r++) acc[r] = 0.0f;
        const float* wrow = W + n*K;
        for (int k = 0; k < K; k++) {
            float wv = wrow[k];
            const float4* xr = (const float4*)&xs[k*MT];
            float4 a0 = xr[0], a1 = xr[1], a2 = xr[2], a3 = xr[3];
            acc[0]  += wv*a0.x;  acc[1]  += wv*a0.y;  acc[2]  += wv*a0.z;  acc[3]  += wv*a0.w;
            acc[4]  += wv*a1.x;  acc[5]  += wv*a1.y;  acc[6]  += wv*a1.z;  acc[7]  += wv*a1.w;
            acc[8]  += wv*a2.x;  acc[9]  += wv*a2.y;  acc[10] += wv*a2.z;  acc[11] += wv*a2.w;
            acc[12] += wv*a3.x;  acc[13] += wv*a3.y;  acc[14] += wv*a3.z;  acc[15] += wv*a3.w;
        }
        float bb = bias[n];
        #pragma unroll
        for (int r = 0; r < MT; r++) out[(m0 + r)*Ncols + n] = acc[r] + bb;
    }
}

// ---------------------------------------------------------------------------
// K3: LSTM scan. One block per (batch, direction); 512 threads.
//     Thread g caches Whh[g][0:125] in VGPRs; h lives in LDS (broadcast reads).
//     Gate order i,f,g,o. Writes h into out[(b*128+t)*250 + dir*125 + j].
// ---------------------------------------------------------------------------
__global__ __launch_bounds__(512, 2)
void lstm_scan(const float* __restrict__ xgf, const float* __restrict__ xgb,
               const float* __restrict__ Whf, const float* __restrict__ Whb,
               float* __restrict__ out) {
    int dir = blockIdx.x & 1;
    int b = blockIdx.x >> 1;
    const float* xg  = dir ? xgb : xgf;
    const float* Whh = dir ? Whb : Whf;
    int off = dir ? D : 0;
    int g = threadIdx.x;

    __shared__ __align__(16) float hbuf[128];
    __shared__ float gbuf[512];

    float w[128];
    #pragma unroll
    for (int k = 0; k < 128; k++)
        w[k] = (g < G4 && k < D) ? Whh[g*D + k] : 0.0f;

    float c = 0.0f;
    if (g < 128) hbuf[g] = 0.0f;
    __syncthreads();

    for (int t = 0; t < N; t++) {
        int tt = dir ? (N - 1 - t) : t;
        float acc0 = (g < G4) ? xg[(b*N + tt)*G4 + g] : 0.0f;
        float acc1 = 0.0f, acc2 = 0.0f, acc3 = 0.0f;
        const float4* h4 = (const float4*)hbuf;
        #pragma unroll
        for (int k4 = 0; k4 < 32; k4++) {
            float4 hv = h4[k4];
            acc0 += w[4*k4 + 0] * hv.x;
            acc1 += w[4*k4 + 1] * hv.y;
            acc2 += w[4*k4 + 2] * hv.z;
            acc3 += w[4*k4 + 3] * hv.w;
        }
        gbuf[g] = (acc0 + acc1) + (acc2 + acc3);
        __syncthreads();
        if (g < D) {
            float iv = gbuf[g];
            float fv = gbuf[D + g];
            float gv = gbuf[2*D + g];
            float ov = gbuf[3*D + g];
            float si = 1.0f / (1.0f + expf(-iv));
            float sf = 1.0f / (1.0f + expf(-fv));
            float so = 1.0f / (1.0f + expf(-ov));
            c = sf*c + si*tanhf(gv);
            float h = so * tanhf(c);
            hbuf[g] = h;
            out[(b*N + tt)*H2 + off + g] = h;
        }
        __syncthreads();
    }
}

// ---------------------------------------------------------------------------
// K4: arc scores + margin + argmax. One block per (b,i); thread j in [0,128).
// ---------------------------------------------------------------------------
__global__ void arc_kernel(const float* __restrict__ wh, const float* __restrict__ wm,
                           const float* __restrict__ esW, const float* __restrict__ esb,
                           const int* __restrict__ ta,
                           float* __restrict__ arc_out, float* __restrict__ tree_out) {
    int bi = blockIdx.x;          // b*128 + i
    int b = bi >> 7;
    int i = bi & 127;
    int j = threadIdx.x;          // 128 threads

    __shared__ float whs[HID];
    __shared__ float es[HID];
    __shared__ float sv[128];
    __shared__ int   si[128];

    if (j < HID) {
        whs[j] = wh[bi*HID + j];
        es[j]  = esW[j];
    }
    __syncthreads();

    const float* wmr = wm + (b*N + j)*HID;
    float acc = 0.0f;
    for (int h = 0; h < HID; h++)
        acc += es[h] * tanhf(whs[h] + wmr[h]);

    int tai = (i == 0) ? 0 : ta[bi];
    float score = acc + esb[0] + 1.0f - ((j == tai) ? 1.0f : 0.0f);
    arc_out[bi*N + j] = score;

    sv[j] = score;
    si[j] = j;
    __syncthreads();
    for (int s = 64; s > 0; s >>= 1) {
        if (j < s) {
            float ov = sv[j + s]; int oi = si[j + s];
            if (ov > sv[j] || (ov == sv[j] && oi < si[j])) { sv[j] = ov; si[j] = oi; }
        }
        __syncthreads();
    }
    if (j == 0) tree_out[bi] = (float)si[0];
}

// ---------------------------------------------------------------------------
// K5: rel scores + argmax. One block (64 threads) per bt.
// ---------------------------------------------------------------------------
__global__ void rel_kernel(const float* __restrict__ rm, const float* __restrict__ rh,
                           const float* __restrict__ lsW, const float* __restrict__ lsb,
                           float* __restrict__ rel_out, float* __restrict__ pred_out) {
    int bt = blockIdx.x;
    int t = threadIdx.x;          // 64 threads

    __shared__ float tv[HID];
    __shared__ float sv[64];
    __shared__ int   si[64];

    for (int h = t; h < HID; h += 64)
        tv[h] = tanhf(rm[bt*HID + h] + rh[bt*HID + h]);
    __syncthreads();

    float score = -1e30f;
    if (t < L) {
        float acc = 0.0f;
        const float* wrow = lsW + t*HID;
        for (int h = 0; h < HID; h++) acc += wrow[h] * tv[h];
        score = acc + lsb[t];
        rel_out[bt*L + t] = score;
    }
    sv[t] = score;
    si[t] = t;
    __syncthreads();
    for (int s = 32; s > 0; s >>= 1) {
        if (t < s) {
            float ov = sv[t + s]; int oi = si[t + s];
            if (ov > sv[t] || (ov == sv[t] && oi < si[t])) { sv[t] = ov; si[t] = oi; }
        }
        __syncthreads();
    }
    if (t == 0) pred_out[bt] = (float)si[0];
}

// ---------------------------------------------------------------------------
extern "C" void kernel_launch(void* const* d_in, const int* in_sizes, int n_in,
                              void* d_out, int out_size, void* d_ws, size_t ws_size,
                              hipStream_t stream) {
    const int*   word_ids    = (const int*)  d_in[0];
    const int*   upos_ids    = (const int*)  d_in[1];
    const int*   target_arcs = (const int*)  d_in[2];
    const float* wlookup     = (const float*)d_in[3];
    const float* tlookup     = (const float*)d_in[4];
    const float* l0f_Wih = (const float*)d_in[5];
    const float* l0f_Whh = (const float*)d_in[6];
    const float* l0f_b   = (const float*)d_in[7];
    const float* l0b_Wih = (const float*)d_in[8];
    const float* l0b_Whh = (const float*)d_in[9];
    const float* l0b_b   = (const float*)d_in[10];
    const float* l1f_Wih = (const float*)d_in[11];
    const float* l1f_Whh = (const float*)d_in[12];
    const float* l1f_b   = (const float*)d_in[13];
    const float* l1b_Wih = (const float*)d_in[14];
    const float* l1b_Whh = (const float*)d_in[15];
    const float* l1b_b   = (const float*)d_in[16];
    const float* eh_W = (const float*)d_in[17];
    const float* eh_b = (const float*)d_in[18];
    const float* em_W = (const float*)d_in[19];
    const float* em_b = (const float*)d_in[20];
    const float* es_W = (const float*)d_in[21];
    const float* es_b = (const float*)d_in[22];
    const float* lh_W = (const float*)d_in[23];
    const float* lh_b = (const float*)d_in[24];
    const float* lm_W = (const float*)d_in[25];
    const float* lm_b = (const float*)d_in[26];
    const float* ls_W = (const float*)d_in[27];
    const float* ls_b = (const float*)d_in[28];

    float* out = (float*)d_out;
    float* trees_out = out;                         // 4096
    float* preds_out = out + BT;                    // 4096
    float* arc_out   = out + 2*BT;                  // 524288
    float* rel_out   = out + 2*BT + BT*N;           // 204800

    float* ws = (float*)d_ws;
    float* words = ws;                     // 512000  (4096*125)
    float* xgF   = ws + 512000;            // 2048000 (4096*500)
    float* xgB   = ws + 2560000;           // 2048000
    float* h0    = ws + 4608000;           // 1024000 (4096*250)
    float* ex    = ws + 5632000;           // 1024000
    // overlays (safe after the stages that used them):
    float* word_h   = words;               // 409600 <= 512000
    float* word_m   = xgF;                 // 409600
    float* rel_mod  = xgF + 409600;
    float* rel_head = xgF + 819200;        // 1228800 <= 2048000

    // 1. embeddings
    embed_kernel<<<BT, 128, 0, stream>>>(word_ids, upos_ids, wlookup, tlookup, words);

    // 2. layer-0 input projections (K=125, N=500)
    proj_kernel<<<BT/MT, 512, 0, stream>>>(words, l0f_Wih, l0f_b, xgF, G4, D, nullptr);
    proj_kernel<<<BT/MT, 512, 0, stream>>>(words, l0b_Wih, l0b_b, xgB, G4, D, nullptr);

    // 3. layer-0 scan -> h0 [4096,250]
    lstm_scan<<<B*2, 512, 0, stream>>>(xgF, xgB, l0f_Whh, l0b_Whh, h0);

    // 4. layer-1 input projections (K=250, N=500)
    proj_kernel<<<BT/MT, 512, 0, stream>>>(h0, l1f_Wih, l1f_b, xgF, G4, H2, nullptr);
    proj_kernel<<<BT/MT, 512, 0, stream>>>(h0, l1b_Wih, l1b_b, xgB, G4, H2, nullptr);

    // 5. layer-1 scan -> word_exprs [4096,250]
    lstm_scan<<<B*2, 512, 0, stream>>>(xgF, xgB, l1f_Whh, l1b_Whh, ex);

    // 6. scorer projections (K=250, N=100)
    proj_kernel<<<BT/MT, 128, 0, stream>>>(ex, eh_W, eh_b, word_h, HID, H2, nullptr);
    proj_kernel<<<BT/MT, 128, 0, stream>>>(ex, em_W, em_b, word_m, HID, H2, nullptr);
    proj_kernel<<<BT/MT, 128, 0, stream>>>(ex, lm_W, lm_b, rel_mod, HID, H2, nullptr);
    proj_kernel<<<BT/MT, 128, 0, stream>>>(ex, lh_W, lh_b, rel_head, HID, H2, target_arcs);

    // 7. arc scores + margin + argmax
    arc_kernel<<<BT, 128, 0, stream>>>(word_h, word_m, es_W, es_b, target_arcs,
                                       arc_out, trees_out);

    // 8. rel scores + argmax
    rel_kernel<<<BT, 64, 0, stream>>>(rel_mod, rel_head, ls_W, ls_b, rel_out, preds_out);
}

// Round 2
// 878.939 us; speedup vs baseline: 1.4166x; 1.4166x over previous
//
#include <hip/hip_runtime.h>
#include <hip/hip_bf16.h>
#include <math.h>

// Problem constants
#define B 32
#define N 128
#define BT (B*N)          // 4096
#define WD 100
#define UD 25
#define D 125             // LSTM hidden per direction
#define G4 (4*D)          // 500 gates
#define H2 (2*D)          // 250
#define HID 100
#define L 50

// Fast, overflow-safe activations on v_exp_f32 (~1ulp; scores shift ~1e-7)
__device__ __forceinline__ float fast_tanh(float x) {
    float e = __expf(2.0f * x);          // inf for large x -> 1 - 0 = 1; 0 for very neg -> -1
    return 1.0f - 2.0f / (e + 1.0f);
}
__device__ __forceinline__ float fast_sigmoid(float x) {
    return 1.0f / (1.0f + __expf(-x));
}
__device__ __forceinline__ float bcast_lane(float v, int k) {
    return __builtin_bit_cast(float, __builtin_amdgcn_readlane(__builtin_bit_cast(int, v), k));
}

// ---------------------------------------------------------------------------
// K1: embedding gather
// ---------------------------------------------------------------------------
__global__ void embed_kernel(const int* __restrict__ wids, const int* __restrict__ uids,
                             const float* __restrict__ wl, const float* __restrict__ tl,
                             float* __restrict__ words) {
    int bt = blockIdx.x;
    int t = threadIdx.x;           // 128 threads
    int wid = wids[bt];
    int uid = uids[bt];
    if (t < WD)       words[bt*D + t] = wl[wid*WD + t];
    else if (t < D)   words[bt*D + t] = tl[uid*UD + (t - WD)];
}

// ---------------------------------------------------------------------------
// K2: projection GEMM  out[m][n] = sum_k x[row(m)][k]*W[n][k] + bias[n]
//     MT=16 rows/block; thread n = one output column. x-tile staged in LDS
//     (stride 17 = conflict-free), broadcast via v_readlane (VALU, not LDS pipe).
// ---------------------------------------------------------------------------
#define MT 16
__global__ void proj_kernel(const float* __restrict__ x, const float* __restrict__ W,
                            const float* __restrict__ bias, float* __restrict__ out,
                            int Ncols, int K, const int* __restrict__ gather_idx) {
    __shared__ float xs[256 * 17 + 16];   // xs[k*17 + r], K<=256
    int m0 = blockIdx.x * MT;
    // stage MT rows, coalesced in k; LDS write stride 17 (coprime 32) = conflict-free
    for (int r = 0; r < MT; r++) {
        int m = m0 + r;
        int row = m;
        if (gather_idx) {
            int bb = m >> 7, np = m & 127;
            row = (bb << 7) + (np == 0 ? 0 : gather_idx[m]);
        }
        for (int k = threadIdx.x; k < K; k += blockDim.x)
            xs[k*17 + r] = x[row*K + k];
    }
    __syncthreads();
    int n = threadIdx.x;
    int lane = n & 63;
    float acc[MT];
    #pragma unroll
    for (int r = 0; r < MT; r++) acc[r] = 0.0f;
    const float* wrow = W + (size_t)(n < Ncols ? n : 0) * K;
    int k0 = 0;
    for (; k0 + 4 <= K; k0 += 4) {
        // lane l holds xs value for (k = k0 + l>>4, r = l&15)
        float xv = xs[k0*17 + ((lane >> 4) * 17) + (lane & 15)];
        float wk0 = wrow[k0], wk1 = wrow[k0+1], wk2 = wrow[k0+2], wk3 = wrow[k0+3];
        #pragma unroll
        for (int r = 0; r < 16; r++) acc[r] = fmaf(wk0, bcast_lane(xv,      r), acc[r]);
        #pragma unroll
        for (int r = 0; r < 16; r++) acc[r] = fmaf(wk1, bcast_lane(xv, 16 + r), acc[r]);
        #pragma unroll
        for (int r = 0; r < 16; r++) acc[r] = fmaf(wk2, bcast_lane(xv, 32 + r), acc[r]);
        #pragma unroll
        for (int r = 0; r < 16; r++) acc[r] = fmaf(wk3, bcast_lane(xv, 48 + r), acc[r]);
    }
    for (; k0 < K; k0++) {                 // tail (K=125 -> 1, K=250 -> 2)
        float xv = xs[k0*17 + (lane & 15)];   // 16 addrs, broadcast within bank = free
        float wk = wrow[k0];
        #pragma unroll
        for (int r = 0; r < 16; r++) acc[r] = fmaf(wk, bcast_lane(xv, r), acc[r]);
    }
    if (n < Ncols) {
        float bb = bias[n];
        #pragma unroll
        for (int r = 0; r < MT; r++) out[(size_t)(m0 + r)*Ncols + n] = acc[r] + bb;
    }
}

// ---------------------------------------------------------------------------
// K3: LSTM scan. One block per (batch, direction); 512 threads.
//     Thread g holds Whh[g][:] in VGPRs; h broadcast via readlane; xg prefetched.
// ---------------------------------------------------------------------------
__global__ __launch_bounds__(512)
void lstm_scan(const float* __restrict__ xgf, const float* __restrict__ xgb,
               const float* __restrict__ Whf, const float* __restrict__ Whb,
               float* __restrict__ out) {
    int dir = blockIdx.x & 1;
    int b = blockIdx.x >> 1;
    const float* xg  = dir ? xgb : xgf;
    const float* Whh = dir ? Whb : Whf;
    int off = dir ? D : 0;
    int g = threadIdx.x;
    int lane = g & 63;
    bool active = (g < G4);

    __shared__ float hbuf[128];
    __shared__ float gbuf[G4];

    float w[125];
    const float* wr = Whh + (size_t)(active ? g : 0) * D;
    #pragma unroll
    for (int k = 0; k < 125; k++) w[k] = wr[k];

    float c = 0.0f;
    if (g < 128) hbuf[g] = 0.0f;
    __syncthreads();

    const float* xgb_ = xg + (size_t)b * N * G4;
    float x_next = active ? xgb_[(dir ? (N-1) : 0) * G4 + g] : 0.0f;

    for (int t = 0; t < N; t++) {
        int tt = dir ? (N-1-t) : t;
        float x_cur = x_next;
        float xn = 0.0f;
        if (active && t + 1 < N)               // prefetch next step (hidden behind FMAs)
            xn = xgb_[(dir ? (tt-1) : (tt+1)) * G4 + g];
        // 2 conflict-free LDS reads bring h into lanes; broadcast via readlane (VALU)
        float h0v = hbuf[lane];
        float h1v = hbuf[64 + lane];
        float acc = x_cur;
        #pragma unroll
        for (int k = 0; k < 64; k++)  acc = fmaf(w[k],      bcast_lane(h0v, k), acc);
        #pragma unroll
        for (int k = 0; k < 61; k++)  acc = fmaf(w[64 + k], bcast_lane(h1v, k), acc);
        x_next = xn;
        if (active) gbuf[g] = acc;
        __syncthreads();
        if (g < D) {
            float iv = gbuf[g], fv = gbuf[D+g], gv = gbuf[2*D+g], ov = gbuf[3*D+g];
            float si = fast_sigmoid(iv);
            float sf = fast_sigmoid(fv);
            float so = fast_sigmoid(ov);
            c = sf * c + si * fast_tanh(gv);
            float h = so * fast_tanh(c);
            hbuf[g] = h;
            out[(size_t)(b*N + tt)*H2 + off + g] = h;
        }
        __syncthreads();
    }
}

// ---------------------------------------------------------------------------
// K4: arc scores + margin + argmax. Block per (b, 4-i tile); 128 threads (j).
//     wm[b] rows staged in LDS stride 101 (conflict-free per-lane walks).
// ---------------------------------------------------------------------------
#define ITILE 4
__global__ __launch_bounds__(128)
void arc_kernel(const float* __restrict__ wh, const float* __restrict__ wm,
                const float* __restrict__ esW, const float* __restrict__ esb,
                const int* __restrict__ ta,
                float* __restrict__ arc_out, float* __restrict__ tree_out) {
    int blk = blockIdx.x;             // b*32 + it
    int b = blk >> 5, it = blk & 31;
    int j = threadIdx.x;              // 128 threads

    __shared__ float wms[128 * 101];
    __shared__ float whs[ITILE][HID];
    __shared__ float es[HID];
    __shared__ float sv[128];
    __shared__ int   si[128];

    for (int e = j; e < 128 * HID; e += 128) {
        int r = e / HID, h = e - r * HID;
        wms[r*101 + h] = wm[(size_t)b*N*HID + e];
    }
    for (int e = j; e < ITILE * HID; e += 128) {
        int ii = e / HID, h = e - ii * HID;
        whs[ii][h] = wh[(size_t)(b*N + it*ITILE + ii)*HID + h];
    }
    if (j < HID) es[j] = esW[j];
    __syncthreads();

    float eb = esb[0];
    const float* wmr = &wms[j * 101];
    for (int ii = 0; ii < ITILE; ii++) {
        int i = it * ITILE + ii;
        int bi = b * N + i;
        float acc = 0.0f;
        for (int h = 0; h < HID; h++)
            acc = fmaf(es[h], fast_tanh(whs[ii][h] + wmr[h]), acc);
        int tai = (i == 0) ? 0 : ta[bi];
        float score = acc + eb + 1.0f - ((j == tai) ? 1.0f : 0.0f);
        arc_out[(size_t)bi*N + j] = score;
        sv[j] = score; si[j] = j;
        __syncthreads();
        for (int s = 64; s; s >>= 1) {
            if (j < s) {
                float ov = sv[j+s]; int oi = si[j+s];
                if (ov > sv[j] || (ov == sv[j] && oi < si[j])) { sv[j] = ov; si[j] = oi; }
            }
            __syncthreads();
        }
        if (j == 0) tree_out[bi] = (float)si[0];
        __syncthreads();
    }
}

// ---------------------------------------------------------------------------
// K5: rel scores + argmax. One block (64 threads) per bt.
// ---------------------------------------------------------------------------
__global__ void rel_kernel(const float* __restrict__ rm, const float* __restrict__ rh,
                           const float* __restrict__ lsW, const float* __restrict__ lsb,
                           float* __restrict__ rel_out, float* __restrict__ pred_out) {
    int bt = blockIdx.x;
    int t = threadIdx.x;          // 64 threads

    __shared__ float tv[HID];
    __shared__ float sv[64];
    __shared__ int   si[64];

    for (int h = t; h < HID; h += 64)
        tv[h] = fast_tanh(rm[bt*HID + h] + rh[bt*HID + h]);
    __syncthreads();

    float score = -1e30f;
    if (t < L) {
        float acc = 0.0f;
        const float* wrow = lsW + t*HID;
        for (int h = 0; h < HID; h++) acc = fmaf(wrow[h], tv[h], acc);
        score = acc + lsb[t];
        rel_out[bt*L + t] = score;
    }
    sv[t] = score;
    si[t] = t;
    __syncthreads();
    for (int s = 32; s; s >>= 1) {
        if (t < s) {
            float ov = sv[t + s]; int oi = si[t + s];
            if (ov > sv[t] || (ov == sv[t] && oi < si[t])) { sv[t] = ov; si[t] = oi; }
        }
        __syncthreads();
    }
    if (t == 0) pred_out[bt] = (float)si[0];
}

// ---------------------------------------------------------------------------
extern "C" void kernel_launch(void* const* d_in, const int* in_sizes, int n_in,
                              void* d_out, int out_size, void* d_ws, size_t ws_size,
                              hipStream_t stream) {
    const int*   word_ids    = (const int*)  d_in[0];
    const int*   upos_ids    = (const int*)  d_in[1];
    const int*   target_arcs = (const int*)  d_in[2];
    const float* wlookup     = (const float*)d_in[3];
    const float* tlookup     = (const float*)d_in[4];
    const float* l0f_Wih = (const float*)d_in[5];
    const float* l0f_Whh = (const float*)d_in[6];
    const float* l0f_b   = (const float*)d_in[7];
    const float* l0b_Wih = (const float*)d_in[8];
    const float* l0b_Whh = (const float*)d_in[9];
    const float* l0b_b   = (const float*)d_in[10];
    const float* l1f_Wih = (const float*)d_in[11];
    const float* l1f_Whh = (const float*)d_in[12];
    const float* l1f_b   = (const float*)d_in[13];
    const float* l1b_Wih = (const float*)d_in[14];
    const float* l1b_Whh = (const float*)d_in[15];
    const float* l1b_b   = (const float*)d_in[16];
    const float* eh_W = (const float*)d_in[17];
    const float* eh_b = (const float*)d_in[18];
    const float* em_W = (const float*)d_in[19];
    const float* em_b = (const float*)d_in[20];
    const float* es_W = (const float*)d_in[21];
    const float* es_b = (const float*)d_in[22];
    const float* lh_W = (const float*)d_in[23];
    const float* lh_b = (const float*)d_in[24];
    const float* lm_W = (const float*)d_in[25];
    const float* lm_b = (const float*)d_in[26];
    const float* ls_W = (const float*)d_in[27];
    const float* ls_b = (const float*)d_in[28];

    float* out = (float*)d_out;
    float* trees_out = out;                         // 4096
    float* preds_out = out + BT;                    // 4096
    float* arc_out   = out + 2*BT;                  // 524288
    float* rel_out   = out + 2*BT + BT*N;           // 204800

    float* ws = (float*)d_ws;
    float* words = ws;                     // 512000  (4096*125)
    float* xgF   = ws + 512000;            // 2048000 (4096*500)
    float* xgB   = ws + 2560000;           // 2048000
    float* h0    = ws + 4608000;           // 1024000 (4096*250)
    float* ex    = ws + 5632000;           // 1024000
    // overlays (safe after the stages that used them):
    float* word_h   = words;               // 409600 <= 512000
    float* word_m   = xgF;                 // 409600
    float* rel_mod  = xgF + 409600;
    float* rel_head = xgF + 819200;        // 1228800 <= 2048000

    // 1. embeddings
    embed_kernel<<<BT, 128, 0, stream>>>(word_ids, upos_ids, wlookup, tlookup, words);

    // 2. layer-0 input projections (K=125, N=500)
    proj_kernel<<<BT/MT, 512, 0, stream>>>(words, l0f_Wih, l0f_b, xgF, G4, D, nullptr);
    proj_kernel<<<BT/MT, 512, 0, stream>>>(words, l0b_Wih, l0b_b, xgB, G4, D, nullptr);

    // 3. layer-0 scan -> h0 [4096,250]
    lstm_scan<<<B*2, 512, 0, stream>>>(xgF, xgB, l0f_Whh, l0b_Whh, h0);

    // 4. layer-1 input projections (K=250, N=500)
    proj_kernel<<<BT/MT, 512, 0, stream>>>(h0, l1f_Wih, l1f_b, xgF, G4, H2, nullptr);
    proj_kernel<<<BT/MT, 512, 0, stream>>>(h0, l1b_Wih, l1b_b, xgB, G4, H2, nullptr);

    // 5. layer-1 scan -> word_exprs [4096,250]
    lstm_scan<<<B*2, 512, 0, stream>>>(xgF, xgB, l1f_Whh, l1b_Whh, ex);

    // 6. scorer projections (K=250, N=100)
    proj_kernel<<<BT/MT, 128, 0, stream>>>(ex, eh_W, eh_b, word_h, HID, H2, nullptr);
    proj_kernel<<<BT/MT, 128, 0, stream>>>(ex, em_W, em_b, word_m, HID, H2, nullptr);
    proj_kernel<<<BT/MT, 128, 0, stream>>>(ex, lm_W, lm_b, rel_mod, HID, H2, nullptr);
    proj_kernel<<<BT/MT, 128, 0, stream>>>(ex, lh_W, lh_b, rel_head, HID, H2, target_arcs);

    // 7. arc scores + margin + argmax
    arc_kernel<<<BT/ITILE, 128, 0, stream>>>(word_h, word_m, es_W, es_b, target_arcs,
                                             arc_out, trees_out);

    // 8. rel scores + argmax
    rel_kernel<<<BT, 64, 0, stream>>>(rel_mod, rel_head, ls_W, ls_b, rel_out, preds_out);
}

// Round 3
// 758.295 us; speedup vs baseline: 1.6420x; 1.1591x over previous
//
#include <hip/hip_runtime.h>
#include <hip/hip_bf16.h>
#include <math.h>

// Problem constants
#define B 32
#define N 128
#define BT (B*N)          // 4096
#define WD 100
#define UD 25
#define D 125             // LSTM hidden per direction
#define G4 (4*D)          // 500 gates
#define H2 (2*D)          // 250
#define HID 100
#define L 50

// Fast, overflow-safe activations on v_exp_f32
__device__ __forceinline__ float fast_tanh(float x) {
    float e = __expf(2.0f * x);
    return 1.0f - 2.0f / (e + 1.0f);
}
__device__ __forceinline__ float fast_sigmoid(float x) {
    return 1.0f / (1.0f + __expf(-x));
}
__device__ __forceinline__ float bcast_lane(float v, int k) {
    return __builtin_bit_cast(float, __builtin_amdgcn_readlane(__builtin_bit_cast(int, v), k));
}

// ---------------------------------------------------------------------------
// K0a: combined-bias setup (b_l0[1000], b_l1[1000], b_s3[300])
// ---------------------------------------------------------------------------
__global__ void bias_setup(const float* __restrict__ l0f_b, const float* __restrict__ l0b_b,
                           const float* __restrict__ l1f_b, const float* __restrict__ l1b_b,
                           const float* __restrict__ eh_b, const float* __restrict__ em_b,
                           const float* __restrict__ lm_b,
                           float* __restrict__ b_l0, float* __restrict__ b_l1,
                           float* __restrict__ b_s3) {
    int t = blockIdx.x * blockDim.x + threadIdx.x;
    if (t < 500)        b_l0[t] = l0f_b[t];
    else if (t < 1000)  b_l0[t] = l0b_b[t-500];
    else if (t < 1500)  b_l1[t-1000] = l1f_b[t-1000];
    else if (t < 2000)  b_l1[t-1000] = l1b_b[t-1500];
    else if (t < 2100)  b_s3[t-2000] = eh_b[t-2000];
    else if (t < 2200)  b_s3[t-2000] = em_b[t-2100];
    else if (t < 2300)  b_s3[t-2000] = lm_b[t-2200];
}

// ---------------------------------------------------------------------------
// K0b: weight transpose  out[k*ldo + coff + n] = in[n*C + k]   (n = blockIdx)
// ---------------------------------------------------------------------------
__global__ void transpose_kernel(const float* __restrict__ in, int C,
                                 float* __restrict__ out, int ldo, int coff) {
    int n = blockIdx.x;
    for (int k = threadIdx.x; k < C; k += blockDim.x)
        out[(size_t)k*ldo + coff + n] = in[(size_t)n*C + k];
}

// ---------------------------------------------------------------------------
// K1: embedding gather
// ---------------------------------------------------------------------------
__global__ void embed_kernel(const int* __restrict__ wids, const int* __restrict__ uids,
                             const float* __restrict__ wl, const float* __restrict__ tl,
                             float* __restrict__ words) {
    int bt = blockIdx.x;
    int t = threadIdx.x;           // 128 threads
    int wid = wids[bt];
    int uid = uids[bt];
    if (t < WD)       words[bt*D + t] = wl[wid*WD + t];
    else if (t < D)   words[bt*D + t] = tl[uid*UD + (t - WD)];
}

// ---------------------------------------------------------------------------
// K2: projection GEMM, transposed weights.
//     out[m][n] = sum_k x[row(m)][k] * WT[k][n] + bias[n]
//     WT loads coalesced across n. x-tile in LDS, broadcast via readlane.
// ---------------------------------------------------------------------------
#define MT 16
__global__ void proj_t(const float* __restrict__ x, const float* __restrict__ WT,
                       const float* __restrict__ bias, float* __restrict__ out,
                       int Ncols, int K, int ldx, const int* __restrict__ gather_idx) {
    __shared__ float xs[250 * 17 + 16];   // xs[k*17 + r]
    int m0 = blockIdx.x * MT;
    for (int r = 0; r < MT; r++) {
        int m = m0 + r;
        int row = m;
        if (gather_idx) {
            int bb = m >> 7, np = m & 127;
            row = (bb << 7) + (np == 0 ? 0 : gather_idx[m]);
        }
        for (int k = threadIdx.x; k < K; k += blockDim.x)
            xs[k*17 + r] = x[(size_t)row*ldx + k];
    }
    __syncthreads();
    int n = threadIdx.x;
    int nn = (n < Ncols) ? n : (Ncols - 1);      // clamp for safe loads
    int lane = n & 63;
    float acc[MT];
    #pragma unroll
    for (int r = 0; r < MT; r++) acc[r] = 0.0f;
    int k0 = 0;
    for (; k0 + 4 <= K; k0 += 4) {
        // lane l holds xs value for (k = k0 + (l>>4), r = l&15)
        float xv = xs[k0*17 + (lane >> 4) * 17 + (lane & 15)];
        float wk0 = WT[(size_t)(k0    )*Ncols + nn];
        float wk1 = WT[(size_t)(k0 + 1)*Ncols + nn];
        float wk2 = WT[(size_t)(k0 + 2)*Ncols + nn];
        float wk3 = WT[(size_t)(k0 + 3)*Ncols + nn];
        #pragma unroll
        for (int r = 0; r < 16; r++) acc[r] = fmaf(wk0, bcast_lane(xv,      r), acc[r]);
        #pragma unroll
        for (int r = 0; r < 16; r++) acc[r] = fmaf(wk1, bcast_lane(xv, 16 + r), acc[r]);
        #pragma unroll
        for (int r = 0; r < 16; r++) acc[r] = fmaf(wk2, bcast_lane(xv, 32 + r), acc[r]);
        #pragma unroll
        for (int r = 0; r < 16; r++) acc[r] = fmaf(wk3, bcast_lane(xv, 48 + r), acc[r]);
    }
    for (; k0 < K; k0++) {                 // tail (K=125 -> 1, K=250 -> 2)
        float xv = xs[k0*17 + (lane & 15)];
        float wk = WT[(size_t)k0*Ncols + nn];
        #pragma unroll
        for (int r = 0; r < 16; r++) acc[r] = fmaf(wk, bcast_lane(xv, r), acc[r]);
    }
    if (n < Ncols) {
        float bb = bias[n];
        #pragma unroll
        for (int r = 0; r < MT; r++) out[(size_t)(m0 + r)*Ncols + n] = acc[r] + bb;
    }
}

// ---------------------------------------------------------------------------
// K3: LSTM scan. One block per (batch, direction); 512 threads.
//     Thread g holds Whh[g][:] in VGPRs (pinned via asm); h via readlane.
//     xg is the fused [m][1000] buffer (fwd gates 0..499, bwd 500..999).
// ---------------------------------------------------------------------------
__global__ __launch_bounds__(512)
void lstm_scan(const float* __restrict__ xgc,
               const float* __restrict__ Whf, const float* __restrict__ Whb,
               float* __restrict__ out) {
    int dir = blockIdx.x & 1;
    int b = blockIdx.x >> 1;
    const float* Whh = dir ? Whb : Whf;
    int off = dir ? D : 0;
    int g = threadIdx.x;
    int lane = g & 63;
    bool active = (g < G4);

    __shared__ float hbuf[128];
    __shared__ float gbuf[G4];

    float w[125];
    {
        const float* wr = Whh + (size_t)(active ? g : 0) * D;
        #pragma unroll
        for (int k = 0; k < 125; k++) w[k] = wr[k];
    }
    // pin w[] in VGPRs: opaque def prevents the allocator from rematerializing
    // the global loads inside the t-loop (round-2 showed VGPR=76 => spilled-to-reload)
    #pragma unroll
    for (int k = 0; k < 125; k++) asm volatile("" : "+v"(w[k]));

    float c = 0.0f;
    if (g < 128) hbuf[g] = 0.0f;
    __syncthreads();

    const float* xb = xgc + (size_t)b * N * 1000 + dir * 500;
    float x_next = active ? xb[(size_t)(dir ? (N-1) : 0) * 1000 + g] : 0.0f;

    for (int t = 0; t < N; t++) {
        int tt = dir ? (N-1-t) : t;
        float x_cur = x_next;
        float xn = 0.0f;
        if (active && t + 1 < N)
            xn = xb[(size_t)(dir ? (tt-1) : (tt+1)) * 1000 + g];
        float h0v = hbuf[lane];
        float h1v = hbuf[64 + lane];
        float a0 = x_cur, a1 = 0.0f, a2 = 0.0f, a3 = 0.0f;
        #pragma unroll
        for (int k = 0; k < 64; k += 4) {
            a0 = fmaf(w[k],   bcast_lane(h0v, k),   a0);
            a1 = fmaf(w[k+1], bcast_lane(h0v, k+1), a1);
            a2 = fmaf(w[k+2], bcast_lane(h0v, k+2), a2);
            a3 = fmaf(w[k+3], bcast_lane(h0v, k+3), a3);
        }
        #pragma unroll
        for (int k = 0; k < 60; k += 4) {
            a0 = fmaf(w[64+k],   bcast_lane(h1v, k),   a0);
            a1 = fmaf(w[64+k+1], bcast_lane(h1v, k+1), a1);
            a2 = fmaf(w[64+k+2], bcast_lane(h1v, k+2), a2);
            a3 = fmaf(w[64+k+3], bcast_lane(h1v, k+3), a3);
        }
        a0 = fmaf(w[124], bcast_lane(h1v, 60), a0);
        x_next = xn;
        if (active) gbuf[g] = (a0 + a1) + (a2 + a3);
        __syncthreads();
        if (g < D) {
            float iv = gbuf[g], fv = gbuf[D+g], gv = gbuf[2*D+g], ov = gbuf[3*D+g];
            float si = fast_sigmoid(iv);
            float sf = fast_sigmoid(fv);
            float so = fast_sigmoid(ov);
            c = sf * c + si * fast_tanh(gv);
            float h = so * fast_tanh(c);
            hbuf[g] = h;
            out[(size_t)(b*N + tt)*H2 + off + g] = h;
        }
        __syncthreads();
    }
}

// ---------------------------------------------------------------------------
// K4: arc scores + margin + argmax. Block per (b, 4-i tile); 128 threads (j).
//     wh/wm live in the fused s3 buffer [m][300]: wh at +0, wm at +100.
// ---------------------------------------------------------------------------
#define ITILE 4
__global__ __launch_bounds__(128)
void arc_kernel(const float* __restrict__ s3,
                const float* __restrict__ esW, const float* __restrict__ esb,
                const int* __restrict__ ta,
                float* __restrict__ arc_out, float* __restrict__ tree_out) {
    int blk = blockIdx.x;             // b*32 + it
    int b = blk >> 5, it = blk & 31;
    int j = threadIdx.x;              // 128 threads

    __shared__ float wms[128 * 101];
    __shared__ float whs[ITILE][HID];
    __shared__ float es[HID];
    __shared__ float sv[128];
    __shared__ int   si[128];

    for (int e = j; e < 128 * HID; e += 128) {
        int r = e / HID, h = e - r * HID;
        wms[r*101 + h] = s3[(size_t)(b*N + r)*300 + 100 + h];
    }
    for (int e = j; e < ITILE * HID; e += 128) {
        int ii = e / HID, h = e - ii * HID;
        whs[ii][h] = s3[(size_t)(b*N + it*ITILE + ii)*300 + h];
    }
    if (j < HID) es[j] = esW[j];
    __syncthreads();

    float eb = esb[0];
    const float* wmr = &wms[j * 101];
    for (int ii = 0; ii < ITILE; ii++) {
        int i = it * ITILE + ii;
        int bi = b * N + i;
        float acc = 0.0f;
        for (int h = 0; h < HID; h++)
            acc = fmaf(es[h], fast_tanh(whs[ii][h] + wmr[h]), acc);
        int tai = (i == 0) ? 0 : ta[bi];
        float score = acc + eb + 1.0f - ((j == tai) ? 1.0f : 0.0f);
        arc_out[(size_t)bi*N + j] = score;
        sv[j] = score; si[j] = j;
        __syncthreads();
        for (int s = 64; s; s >>= 1) {
            if (j < s) {
                float ov = sv[j+s]; int oi = si[j+s];
                if (ov > sv[j] || (ov == sv[j] && oi < si[j])) { sv[j] = ov; si[j] = oi; }
            }
            __syncthreads();
        }
        if (j == 0) tree_out[bi] = (float)si[0];
        __syncthreads();
    }
}

// ---------------------------------------------------------------------------
// K5: rel scores + argmax. One block (64 threads) per bt.
//     rel_mod at s3[m][200..300); rel_head separate [m][100].
// ---------------------------------------------------------------------------
__global__ void rel_kernel(const float* __restrict__ s3, const float* __restrict__ rh,
                           const float* __restrict__ lsW, const float* __restrict__ lsb,
                           float* __restrict__ rel_out, float* __restrict__ pred_out) {
    int bt = blockIdx.x;
    int t = threadIdx.x;          // 64 threads

    __shared__ float tv[HID];
    __shared__ float sv[64];
    __shared__ int   si[64];

    for (int h = t; h < HID; h += 64)
        tv[h] = fast_tanh(s3[(size_t)bt*300 + 200 + h] + rh[(size_t)bt*HID + h]);
    __syncthreads();

    float score = -1e30f;
    if (t < L) {
        float acc = 0.0f;
        const float* wrow = lsW + t*HID;
        for (int h = 0; h < HID; h++) acc = fmaf(wrow[h], tv[h], acc);
        score = acc + lsb[t];
        rel_out[(size_t)bt*L + t] = score;
    }
    sv[t] = score;
    si[t] = t;
    __syncthreads();
    for (int s = 32; s; s >>= 1) {
        if (t < s) {
            float ov = sv[t + s]; int oi = si[t + s];
            if (ov > sv[t] || (ov == sv[t] && oi < si[t])) { sv[t] = ov; si[t] = oi; }
        }
        __syncthreads();
    }
    if (t == 0) pred_out[bt] = (float)si[0];
}

// ---------------------------------------------------------------------------
extern "C" void kernel_launch(void* const* d_in, const int* in_sizes, int n_in,
                              void* d_out, int out_size, void* d_ws, size_t ws_size,
                              hipStream_t stream) {
    const int*   word_ids    = (const int*)  d_in[0];
    const int*   upos_ids    = (const int*)  d_in[1];
    const int*   target_arcs = (const int*)  d_in[2];
    const float* wlookup     = (const float*)d_in[3];
    const float* tlookup     = (const float*)d_in[4];
    const float* l0f_Wih = (const float*)d_in[5];
    const float* l0f_Whh = (const float*)d_in[6];
    const float* l0f_b   = (const float*)d_in[7];
    const float* l0b_Wih = (const float*)d_in[8];
    const float* l0b_Whh = (const float*)d_in[9];
    const float* l0b_b   = (const float*)d_in[10];
    const float* l1f_Wih = (const float*)d_in[11];
    const float* l1f_Whh = (const float*)d_in[12];
    const float* l1f_b   = (const float*)d_in[13];
    const float* l1b_Wih = (const float*)d_in[14];
    const float* l1b_Whh = (const float*)d_in[15];
    const float* l1b_b   = (const float*)d_in[16];
    const float* eh_W = (const float*)d_in[17];
    const float* eh_b = (const float*)d_in[18];
    const float* em_W = (const float*)d_in[19];
    const float* em_b = (const float*)d_in[20];
    const float* es_W = (const float*)d_in[21];
    const float* es_b = (const float*)d_in[22];
    const float* lh_W = (const float*)d_in[23];
    const float* lh_b = (const float*)d_in[24];
    const float* lm_W = (const float*)d_in[25];
    const float* lm_b = (const float*)d_in[26];
    const float* ls_W = (const float*)d_in[27];
    const float* ls_b = (const float*)d_in[28];

    float* out = (float*)d_out;
    float* trees_out = out;                         // 4096
    float* preds_out = out + BT;                    // 4096
    float* arc_out   = out + 2*BT;                  // 524288
    float* rel_out   = out + 2*BT + BT*N;           // 204800

    float* ws = (float*)d_ws;
    float* A      = ws;                    // 4,096,000: xg fused [m][1000]; later s3 [m][300]
    float* words  = ws + 4096000;          //   512,000
    float* C      = ws + 4608000;          // 1,024,000: h0, then ex
    float* WT_l0  = ws + 5632000;          //   125,000  [125][1000]
    float* WT_l1  = ws + 5757000;          //   250,000  [250][1000]
    float* WT_s3  = ws + 6007000;          //    75,000  [250][300]
    float* WT_lh  = ws + 6082000;          //    25,000  [250][100]
    float* b_l0   = ws + 6107000;          //     1,000
    float* b_l1   = ws + 6108000;          //     1,000
    float* b_s3   = ws + 6109000;          //     1,000 (300 used)
    float* rel_head = ws + 6110000;        //   409,600  [m][100]
    // total 6,519,600 floats = 26.1 MB

    // 0. weight transposes + fused biases
    bias_setup<<<9, 256, 0, stream>>>(l0f_b, l0b_b, l1f_b, l1b_b, eh_b, em_b, lm_b,
                                      b_l0, b_l1, b_s3);
    transpose_kernel<<<500, 128, 0, stream>>>(l0f_Wih, D,  WT_l0, 1000, 0);
    transpose_kernel<<<500, 128, 0, stream>>>(l0b_Wih, D,  WT_l0, 1000, 500);
    transpose_kernel<<<500, 128, 0, stream>>>(l1f_Wih, H2, WT_l1, 1000, 0);
    transpose_kernel<<<500, 128, 0, stream>>>(l1b_Wih, H2, WT_l1, 1000, 500);
    transpose_kernel<<<100, 128, 0, stream>>>(eh_W, H2, WT_s3, 300, 0);
    transpose_kernel<<<100, 128, 0, stream>>>(em_W, H2, WT_s3, 300, 100);
    transpose_kernel<<<100, 128, 0, stream>>>(lm_W, H2, WT_s3, 300, 200);
    transpose_kernel<<<100, 128, 0, stream>>>(lh_W, H2, WT_lh, 100, 0);

    // 1. embeddings
    embed_kernel<<<BT, 128, 0, stream>>>(word_ids, upos_ids, wlookup, tlookup, words);

    // 2. layer-0 input projections, fused fwd+bwd (K=125, N=1000)
    proj_t<<<BT/MT, 1024, 0, stream>>>(words, WT_l0, b_l0, A, 1000, D, D, nullptr);

    // 3. layer-0 scan -> h0 (C)
    lstm_scan<<<B*2, 512, 0, stream>>>(A, l0f_Whh, l0b_Whh, C);

    // 4. layer-1 input projections (K=250, N=1000)
    proj_t<<<BT/MT, 1024, 0, stream>>>(C, WT_l1, b_l1, A, 1000, H2, H2, nullptr);

    // 5. layer-1 scan -> ex (C, overwrites h0)
    lstm_scan<<<B*2, 512, 0, stream>>>(A, l1f_Whh, l1b_Whh, C);

    // 6. scorer projections: eh+em+lm fused (N=300) into A; lh gathered (N=100)
    proj_t<<<BT/MT, 320, 0, stream>>>(C, WT_s3, b_s3, A, 300, H2, H2, nullptr);
    proj_t<<<BT/MT, 128, 0, stream>>>(C, WT_lh, lh_b, rel_head, 100, H2, H2, target_arcs);

    // 7. arc scores + margin + argmax
    arc_kernel<<<BT/ITILE, 128, 0, stream>>>(A, es_W, es_b, target_arcs,
                                             arc_out, trees_out);

    // 8. rel scores + argmax
    rel_kernel<<<BT, 64, 0, stream>>>(A, rel_head, ls_W, ls_b, rel_out, preds_out);
}